// Round 9
// baseline (316.094 us; speedup 1.0000x reference)
//
#include <hip/hip_runtime.h>

// VectorQuantizer on MI355X — R17.
// R16 post-mortem (crash root-caused): per-wave register cut is looser than
// R12's shared cut -> ~36 inserts/row > CAP=32 -> overflow dropped the final-
// max entry on some rows -> ncnt==0 -> rescore slow path ran 0 iterations ->
// bk=0x7fffffff -> OOB gather -> page fault. R17 keeps the register-cut theory
// (kill the per-fire DPP->LDS atomicMax->LDS read serial chain) but makes it
// safe: (1) CAP 32->64 (LDS 58KB, still 2 blocks/CU); (2) cross-wave refresh
// every 8 slots (tighter cut); (3) bulletproof fallback: cnt>CAP => gcnt=-1 =>
// rescore full-8192 exact scan for that row (rare, wave-uniform); bk&=8191
// crash-guard. Geometry/k-loop = R14 (proven 180us, no spill).

#define D        256
#define KCODES   8192
#define NROWS    32768
#define MB       64       // rows per block (score)
#define SLOTS    128      // chunk-slots per wave (512 chunks / 4 code-quarters)
#define THREADS  512
#define CAP      64
#define MARGIN   0.03f    // f16 score err bound ~7e-3
#define BIAS     32.0f    // scores shifted positive so int-compare == float-compare
#define NOUT     8388608

typedef _Float16 h8_t __attribute__((ext_vector_type(8)));
typedef float    f4_t __attribute__((ext_vector_type(4)));

__device__ __forceinline__ float clipf(float v) { return fminf(1.0f, fmaxf(-1.0f, v)); }

#define DPP_ROR(x, n) __int_as_float(__builtin_amdgcn_update_dpp( \
    0, __float_as_int(x), 0x120 + (n), 0xF, 0xF, true))
__device__ __forceinline__ float maxrow16(float x) {
  x = fmaxf(x, DPP_ROR(x, 1));
  x = fmaxf(x, DPP_ROR(x, 2));
  x = fmaxf(x, DPP_ROR(x, 4));
  x = fmaxf(x, DPP_ROR(x, 8));
  return x;
}

// ---- pack f16 codebook, chunk-major fragment order + numpy-order sum(e^2) ----
__global__ void vq_packsetup(const float* __restrict__ emb, _Float16* __restrict__ femb,
                             float* __restrict__ senp, float* __restrict__ ekkb,
                             float* __restrict__ lossacc) {
  const int t = blockIdx.x;   // 1024 blocks
  if (t == 0 && threadIdx.x == 0) lossacc[0] = 0.0f;
  {
    int g = t * 256 + threadIdx.x;   // one global 16B unit per thread (262144)
    int ch = g >> 9, u = g & 511;
    int kc = u >> 6, ln = u & 63;
    int code = ch * 16 + (ln & 15);
    int k0 = kc * 32 + (ln >> 4) * 8;
    const float* sp = emb + (size_t)code * D + k0;
    f4_t v0 = *(const f4_t*)sp, v1 = *(const f4_t*)(sp + 4);
    h8_t h;
    h[0] = (_Float16)v0[0]; h[1] = (_Float16)v0[1];
    h[2] = (_Float16)v0[2]; h[3] = (_Float16)v0[3];
    h[4] = (_Float16)v1[0]; h[5] = (_Float16)v1[1];
    h[6] = (_Float16)v1[2]; h[7] = (_Float16)v1[3];
    *(h8_t*)(femb + (size_t)g * 8) = h;
  }
  if (t < 256) {   // senp/ekkb: byte-identical computation to previous rounds
    const int lane = threadIdx.x & 63;
    const int w    = threadIdx.x >> 6;
    const int jdx  = lane & 15, hf = jdx >> 3, jj = jdx & 7;
    #pragma unroll
    for (int cc = 0; cc < 2; ++cc) {
      int k = t * 32 + w * 8 + cc * 4 + (lane >> 4);
      const float* base = emb + (size_t)k * D + hf * 128 + jj;
      float v = base[0];
      float r = v * v;
      #pragma unroll
      for (int m = 1; m < 16; ++m) { v = base[8 * m]; r += v * v; }
      r += __shfl_xor(r, 1, 64);
      r += __shfl_xor(r, 2, 64);
      r += __shfl_xor(r, 4, 64);
      r += __shfl_xor(r, 8, 64);
      if (jdx == 0) { senp[k] = r; ekkb[k] = 0.5f * r - BIAS; }
    }
  }
}

// ---------------- score: MFMA + register-cut filter -> COMPACTED lists ----------------
__global__ void __launch_bounds__(THREADS, 4)
vq_score(const float* __restrict__ xin, const _Float16* __restrict__ femb,
         const float* __restrict__ ekkb, int* __restrict__ gcnt,
         unsigned short* __restrict__ gcand) {
  __shared__ alignas(16) char Astage[32768];   // 64 rows x 256 k f16, fragment order
  __shared__ int rowmaxI[MB];
  __shared__ int cnt[MB];
  __shared__ int ncnt[MB];
  __shared__ unsigned short cand[MB][CAP];     // 8 KB
  __shared__ float scoref[MB][CAP];            // 16 KB; total ~58 KB -> 2 blocks/CU

  const int tid  = threadIdx.x;
  const int lane = tid & 63;
  const int wid  = tid >> 6;     // 0..7
  const int l15  = lane & 15;
  const int quad = lane >> 4;
  const int rw   = wid >> 2;     // 0..1 : 32-row half
  const int cq   = wid & 3;      // 0..3 : code quarter
  const int r0   = blockIdx.x * MB;

  for (int i = tid; i < MB; i += THREADS) { rowmaxI[i] = 0; cnt[i] = 0; ncnt[i] = 0; }

  // stage A (clip + f16, chunk-major fragment order: 64 rows x 256 k = 2048 units)
  #pragma unroll
  for (int j = 0; j < 4; ++j) {
    int c = j * THREADS + tid;          // 0..2047
    int ms = c >> 9, kc = (c >> 6) & 7, ln = c & 63;
    int row = ms * 16 + (ln & 15);
    int k0 = kc * 32 + (ln >> 4) * 8;
    const float* ap = xin + (size_t)(r0 + row) * D + k0;
    f4_t v0 = *(const f4_t*)ap, v1 = *(const f4_t*)(ap + 4);
    h8_t h;
    h[0] = (_Float16)clipf(v0[0]); h[1] = (_Float16)clipf(v0[1]);
    h[2] = (_Float16)clipf(v0[2]); h[3] = (_Float16)clipf(v0[3]);
    h[4] = (_Float16)clipf(v1[0]); h[5] = (_Float16)clipf(v1[1]);
    h[6] = (_Float16)clipf(v1[2]); h[7] = (_Float16)clipf(v1[3]);
    *(h8_t*)(Astage + (size_t)c * 16) = h;
  }
  __syncthreads();

  // A fragments -> registers: 32 rows per wave (rw half), 64 VGPR
  h8_t afrag[2][8];
  #pragma unroll
  for (int m = 0; m < 2; ++m)
    #pragma unroll
    for (int kc = 0; kc < 8; ++kc)
      afrag[m][kc] = *(const h8_t*)(Astage +
          (size_t)(((rw * 2 + m) * 512 + kc * 64 + lane) * 16));

  // per-lane running row maxes (group-uniform via maxrow16): rml[m][r]
  float rml[2][4];
  #pragma unroll
  for (int m = 0; m < 2; ++m)
    #pragma unroll
    for (int r = 0; r < 4; ++r) rml[m][r] = -1e30f;

  // ---- K-loop: half-slot split (R14 form, proven no-spill).
  h8_t bufA[4], bufB[4]; float ekcur;
  {
    const _Float16* bb = femb + (size_t)cq * 4096 + lane * 8;
    #pragma unroll
    for (int kc = 0; kc < 4; ++kc) bufA[kc] = *(const h8_t*)(bb + kc * 512);
    #pragma unroll
    for (int kc = 0; kc < 4; ++kc) bufB[kc] = *(const h8_t*)(bb + (4 + kc) * 512);
    ekcur = ekkb[cq * 16 + l15];
  }

  for (int s = 0; s < SLOTS; ++s) {
    const int sn = (s + 1 < SLOTS) ? s + 1 : s;   // clamped prefetch (in-bounds)
    const _Float16* bbn = femb + (size_t)(sn * 4 + cq) * 4096 + lane * 8;

    f4_t acc[2];
    #pragma unroll
    for (int m = 0; m < 2; ++m) { f4_t z = {0.f, 0.f, 0.f, 0.f}; acc[m] = z; }

    // half 0: consume bufA, then immediately re-target it at next slot
    #pragma unroll
    for (int kc = 0; kc < 4; ++kc)
      #pragma unroll
      for (int m = 0; m < 2; ++m)
        acc[m] = __builtin_amdgcn_mfma_f32_16x16x32_f16(afrag[m][kc], bufA[kc], acc[m], 0, 0, 0);
    #pragma unroll
    for (int kc = 0; kc < 4; ++kc) bufA[kc] = *(const h8_t*)(bbn + kc * 512);

    // half 1: consume bufB, then re-target it at next slot
    #pragma unroll
    for (int kc = 0; kc < 4; ++kc)
      #pragma unroll
      for (int m = 0; m < 2; ++m)
        acc[m] = __builtin_amdgcn_mfma_f32_16x16x32_f16(afrag[m][4 + kc], bufB[kc], acc[m], 0, 0, 0);
    #pragma unroll
    for (int kc = 0; kc < 4; ++kc) bufB[kc] = *(const h8_t*)(bbn + (4 + kc) * 512);

    float eknext = ekkb[(sn * 4 + cq) * 16 + l15];

    // ---- epilogue: pure-register cut, no LDS atomics in the hot path ----
    const int ch = s * 4 + cq;
    #pragma unroll
    for (int m = 0; m < 2; ++m) {
      float ts[4];
      #pragma unroll
      for (int r = 0; r < 4; ++r) ts[r] = acc[m][r] - ekcur;
      #pragma unroll
      for (int r = 0; r < 4; ++r) {
        float mm = maxrow16(ts[r]);              // group max -> uniform in 16 lanes
        rml[m][r] = fmaxf(rml[m][r], mm);        // running row max, registers only
        if (ts[r] >= rml[m][r] - MARGIN) {       // rare after early slots
          int row_ = rw * 32 + m * 16 + quad * 4 + r;
          int sidx = atomicAdd(&cnt[row_], 1);
          if (sidx < CAP) {
            cand[row_][sidx]   = (unsigned short)(ch * 16 + l15);
            scoref[row_][sidx] = ts[r];
          }
        }
      }
    }
    ekcur = eknext;

    // cross-wave tightening every 8 slots (4 cq waves share rows) + L2 sync
    if ((s & 7) == 7) {
      #pragma unroll
      for (int m = 0; m < 2; ++m)
        #pragma unroll
        for (int r = 0; r < 4; ++r) {
          int row_ = rw * 32 + m * 16 + quad * 4 + r;
          if (l15 == 0) atomicMax(&rowmaxI[row_], __float_as_int(rml[m][r]));
        }
      __syncthreads();
      #pragma unroll
      for (int m = 0; m < 2; ++m)
        #pragma unroll
        for (int r = 0; r < 4; ++r) {
          int row_ = rw * 32 + m * 16 + quad * 4 + r;
          rml[m][r] = fmaxf(rml[m][r], __int_as_float(rowmaxI[row_]));
        }
    }
  }
  __syncthreads();   // rowmaxI final (published at s=127), cnt/cand final

  // ---- compact vs FINAL row max; overflow rows -> full-rescan sentinel ----
  {
    const int row = tid >> 3, j = tid & 7;       // 8 threads per row
    const int c = cnt[row];
    if (c <= CAP) {                              // complete list: safe to compact
      const float cut = __int_as_float(rowmaxI[row]) - MARGIN;
      for (int jj = j; jj < c; jj += 8) {
        if (scoref[row][jj] >= cut) {
          int ns = atomicAdd(&ncnt[row], 1);
          gcand[(size_t)(r0 + row) * CAP + ns] = cand[row][jj];
        }
      }
    }
  }
  __syncthreads();
  if (tid < MB) {
    int c = cnt[tid];
    gcnt[r0 + tid] = (c > CAP) ? -1 : ncnt[tid];   // -1 => rescore full scan
  }
}

// ---------------- rescore: nc==1 fast path + exact slow path + full-scan fallback ----------------
// Post-compaction, nc = count of codes within MARGIN of the FINAL f16 max.
// nc==1 => that candidate IS the exact argmin (margin invariant) -> gather+loss.
// nc==-1 (list overflowed in score) => exact argmin over ALL 8192 codes.
__global__ void __launch_bounds__(512)
vq_rescore(const float* __restrict__ xin, const float* __restrict__ emb,
           const float* __restrict__ senp, const int* __restrict__ gcnt,
           const unsigned short* __restrict__ gcand, float* __restrict__ out,
           float* __restrict__ lossacc) {
  __shared__ float xrow[8][D];
  __shared__ float rpart[8][16];
  __shared__ float blksum;
  const int tid  = threadIdx.x;
  const int lane = tid & 63;
  const int wid  = tid >> 6;     // 0..7
  const int g    = lane >> 3;    // candidate slot within batch (0..7)
  const int e    = lane & 7;     // 32-elem octant (0..7)
  const int r0   = blockIdx.x * 64;
  if (tid == 0) blksum = 0.0f;
  __syncthreads();

  const int lane4 = lane * 4;
  float lacc = 0.0f;             // per-lane loss accumulator (deferred reduce)

  // classify this wave's 8 rows (row = wid + rr*8)
  int ncs[8], k0s[8];
  #pragma unroll
  for (int rr = 0; rr < 8; ++rr) {
    int row = r0 + wid + rr * 8;
    ncs[rr] = gcnt[row];
    k0s[rr] = gcand[(size_t)row * CAP];
  }

  // ---- fast rows: batched independent loads (one latency window) ----
  f4_t evs[8], xvs[8];
  #pragma unroll
  for (int rr = 0; rr < 8; ++rr) {
    if (ncs[rr] == 1) {          // wave-uniform branch
      int row = r0 + wid + rr * 8;
      xvs[rr] = *(const f4_t*)(xin + (size_t)row * D + lane4);
      evs[rr] = *(const f4_t*)(emb + (size_t)(k0s[rr] & (KCODES - 1)) * D + lane4);
    }
  }
  #pragma unroll
  for (int rr = 0; rr < 8; ++rr) {
    if (ncs[rr] == 1) {
      int row = r0 + wid + rr * 8;
      f4_t xv = xvs[rr];
      xv[0] = clipf(xv[0]); xv[1] = clipf(xv[1]);
      xv[2] = clipf(xv[2]); xv[3] = clipf(xv[3]);
      f4_t ev = evs[rr];
      *(f4_t*)(out + (size_t)row * D + lane4) = ev;
      #pragma unroll
      for (int i = 0; i < 4; ++i) { float df = ev[i] - xv[i]; lacc += df * df; }
    }
  }

  // ---- slow rows: exact rescore over candidates (or all codes if nc<0) ----
  for (int rr = 0; rr < 8; ++rr) {
    if (ncs[rr] != 1) {          // wave-uniform
      const int row = wid + rr * 8;
      f4_t xv = *(const f4_t*)(xin + (size_t)(r0 + row) * D + lane4);
      xv[0] = clipf(xv[0]); xv[1] = clipf(xv[1]);
      xv[2] = clipf(xv[2]); xv[3] = clipf(xv[3]);
      *(f4_t*)&xrow[wid][lane4] = xv;
      __builtin_amdgcn_wave_barrier();
      if (lane < 16) {   // numpy pairwise sum of x^2 (exact order)
        const int hf = lane >> 3, jj = lane & 7;
        const float* base = &xrow[wid][hf * 128 + jj];
        float v = base[0];
        float rs = v * v;
        #pragma unroll
        for (int m = 1; m < 16; ++m) { v = base[8 * m]; rs += v * v; }
        rpart[wid][lane] = rs;
      }
      __builtin_amdgcn_wave_barrier();
      float p[16];
      #pragma unroll
      for (int j = 0; j < 16; ++j) p[j] = rpart[wid][j];
      float h0 = ((p[0] + p[1]) + (p[2] + p[3])) + ((p[4] + p[5]) + (p[6] + p[7]));
      float h1 = ((p[8] + p[9]) + (p[10] + p[11])) + ((p[12] + p[13]) + (p[14] + p[15]));
      float sx = h0 + h1;

      // hoist this lane's x octant (32 floats)
      f4_t xo[8];
      #pragma unroll
      for (int u = 0; u < 8; ++u) xo[u] = *(const f4_t*)&xrow[wid][e * 32 + u * 4];

      const int nc = ncs[rr];
      const bool fullscan = (nc < 0);
      const int niter = fullscan ? (KCODES >> 3) : ((nc + 7) >> 3);
      const unsigned short* cl = gcand + (size_t)(r0 + row) * CAP;
      float bd = INFINITY; int bk = 0x7fffffff;
      for (int bi = 0; bi < niter; ++bi) {
        int ci = bi * 8 + g;
        bool valid = fullscan ? true : (ci < nc);
        int k = fullscan ? ci : (valid ? (int)cl[ci] : 0);
        const float* ep = emb + (size_t)k * D + e * 32;
        double dd = 0.0;
        #pragma unroll
        for (int u = 0; u < 8; ++u) {
          f4_t ev = *(const f4_t*)(ep + u * 4);
          dd += (double)xo[u][0] * (double)ev[0] + (double)xo[u][1] * (double)ev[1]
              + (double)xo[u][2] * (double)ev[2] + (double)xo[u][3] * (double)ev[3];
        }
        dd += __shfl_xor(dd, 1, 64);
        dd += __shfl_xor(dd, 2, 64);
        dd += __shfl_xor(dd, 4, 64);   // all 8 lanes of the group hold the full dot
        float T1 = sx + senp[k];       // fp32, numpy op order
        float T2 = (float)(2.0 * dd);
        float d  = valid ? (T1 - T2) : INFINITY;
        int   kk = valid ? k : 0x7fffffff;
        if (d < bd || (d == bd && kk < bk)) { bd = d; bk = kk; }
      }
      // cross-group lexicographic argmin (associative & commutative -> exact)
      #pragma unroll
      for (int off = 8; off < 64; off <<= 1) {
        float od = __shfl_xor(bd, off, 64);
        int   ok = __shfl_xor(bk, off, 64);
        if (od < bd || (od == bd && ok < bk)) { bd = od; bk = ok; }
      }
      bk &= (KCODES - 1);   // crash-guard (bk valid by construction; belt+braces)

      f4_t ev = *(const f4_t*)(emb + (size_t)bk * D + lane4);
      *(f4_t*)(out + (size_t)(r0 + row) * D + lane4) = ev;
      #pragma unroll
      for (int i = 0; i < 4; ++i) { float df = ev[i] - xv[i]; lacc += df * df; }
    }
  }

  // one reduce per wave, one LDS atomic per wave, one global atomic per block
  #pragma unroll
  for (int off = 1; off < 64; off <<= 1) lacc += __shfl_xor(lacc, off, 64);
  if (lane == 0) atomicAdd(&blksum, lacc);
  __syncthreads();
  if (tid == 0) atomicAdd(lossacc, blksum);
}

// ---------------- finalize loss ----------------
__global__ void vq_fin(const float* __restrict__ lossacc, float* __restrict__ out) {
  out[NOUT] = 1.25f * lossacc[0] / 8388608.0f;
}

extern "C" void kernel_launch(void* const* d_in, const int* in_sizes, int n_in,
                              void* d_out, int out_size, void* d_ws, size_t ws_size,
                              hipStream_t stream) {
  const float* xin = (const float*)d_in[0];
  const float* emb = (const float*)d_in[1];
  float* out = (float*)d_out;
  _Float16* femb = (_Float16*)d_ws;                 // 4 MB (512 chunks x 8 KB)
  float* F       = (float*)d_ws + 1048576;
  float* senp    = F;                               // 8192
  float* ekkb    = F + 8192;                        // 8192
  float* lossacc = F + 16384;                       // 1
  int*   gcnt    = (int*)(F + 16640);               // 32768 ints
  unsigned short* gcand = (unsigned short*)(F + 16640 + 32768);  // 32768*64 u16
  vq_packsetup<<<dim3(1024), dim3(256), 0, stream>>>(emb, femb, senp, ekkb, lossacc);
  vq_score<<<dim3(NROWS / MB), dim3(THREADS), 0, stream>>>(xin, femb, ekkb, gcnt, gcand);
  vq_rescore<<<dim3(NROWS / 64), dim3(512), 0, stream>>>(xin, emb, senp, gcnt, gcand, out, lossacc);
  vq_fin<<<dim3(1), dim3(1), 0, stream>>>(lossacc, out);
}

// Round 10
// 302.818 us; speedup vs baseline: 1.0438x; 1.0438x over previous
//
#include <hip/hip_runtime.h>

// VectorQuantizer on MI355X — R18.
// R17 post-mortem: register cut w/o gate -> VALUBusy 40->65%, dur 218us. MFMA
// time constant (63us) — the regression is pure unconditional epilogue VALU
// (32 DPP ops/slot) that R12's __any gate used to skip. Epilogue cost is now
// PROVEN first-order. R18 = R12's gate + R17's register cut: per m, fire only
// if __any(ts[r] >= rml[m][r]-MARGIN) (~8 ops quiet); inside fire do maxrow16
// + register rml update + inserts (no LDS atomic/read chain in the K-loop).
// Gate >= insert-cond => can never skip a needed insert; wave cut <= final cut
// => superset invariant; CAP 64 + full-scan fallback retained (R17, proven).
// K-loop/geometry = R14 half-slot (proven no-spill). Zero reg delta vs R17.

#define D        256
#define KCODES   8192
#define NROWS    32768
#define MB       64       // rows per block (score)
#define SLOTS    128      // chunk-slots per wave (512 chunks / 4 code-quarters)
#define THREADS  512
#define CAP      64
#define MARGIN   0.03f    // f16 score err bound ~7e-3
#define BIAS     32.0f    // scores shifted positive so int-compare == float-compare
#define NOUT     8388608

typedef _Float16 h8_t __attribute__((ext_vector_type(8)));
typedef float    f4_t __attribute__((ext_vector_type(4)));

__device__ __forceinline__ float clipf(float v) { return fminf(1.0f, fmaxf(-1.0f, v)); }

#define DPP_ROR(x, n) __int_as_float(__builtin_amdgcn_update_dpp( \
    0, __float_as_int(x), 0x120 + (n), 0xF, 0xF, true))
__device__ __forceinline__ float maxrow16(float x) {
  x = fmaxf(x, DPP_ROR(x, 1));
  x = fmaxf(x, DPP_ROR(x, 2));
  x = fmaxf(x, DPP_ROR(x, 4));
  x = fmaxf(x, DPP_ROR(x, 8));
  return x;
}

// ---- pack f16 codebook, chunk-major fragment order + numpy-order sum(e^2) ----
__global__ void vq_packsetup(const float* __restrict__ emb, _Float16* __restrict__ femb,
                             float* __restrict__ senp, float* __restrict__ ekkb,
                             float* __restrict__ lossacc) {
  const int t = blockIdx.x;   // 1024 blocks
  if (t == 0 && threadIdx.x == 0) lossacc[0] = 0.0f;
  {
    int g = t * 256 + threadIdx.x;   // one global 16B unit per thread (262144)
    int ch = g >> 9, u = g & 511;
    int kc = u >> 6, ln = u & 63;
    int code = ch * 16 + (ln & 15);
    int k0 = kc * 32 + (ln >> 4) * 8;
    const float* sp = emb + (size_t)code * D + k0;
    f4_t v0 = *(const f4_t*)sp, v1 = *(const f4_t*)(sp + 4);
    h8_t h;
    h[0] = (_Float16)v0[0]; h[1] = (_Float16)v0[1];
    h[2] = (_Float16)v0[2]; h[3] = (_Float16)v0[3];
    h[4] = (_Float16)v1[0]; h[5] = (_Float16)v1[1];
    h[6] = (_Float16)v1[2]; h[7] = (_Float16)v1[3];
    *(h8_t*)(femb + (size_t)g * 8) = h;
  }
  if (t < 256) {   // senp/ekkb: byte-identical computation to previous rounds
    const int lane = threadIdx.x & 63;
    const int w    = threadIdx.x >> 6;
    const int jdx  = lane & 15, hf = jdx >> 3, jj = jdx & 7;
    #pragma unroll
    for (int cc = 0; cc < 2; ++cc) {
      int k = t * 32 + w * 8 + cc * 4 + (lane >> 4);
      const float* base = emb + (size_t)k * D + hf * 128 + jj;
      float v = base[0];
      float r = v * v;
      #pragma unroll
      for (int m = 1; m < 16; ++m) { v = base[8 * m]; r += v * v; }
      r += __shfl_xor(r, 1, 64);
      r += __shfl_xor(r, 2, 64);
      r += __shfl_xor(r, 4, 64);
      r += __shfl_xor(r, 8, 64);
      if (jdx == 0) { senp[k] = r; ekkb[k] = 0.5f * r - BIAS; }
    }
  }
}

// ---------------- score: MFMA + gated register-cut filter -> COMPACTED lists ----------------
__global__ void __launch_bounds__(THREADS, 4)
vq_score(const float* __restrict__ xin, const _Float16* __restrict__ femb,
         const float* __restrict__ ekkb, int* __restrict__ gcnt,
         unsigned short* __restrict__ gcand) {
  __shared__ alignas(16) char Astage[32768];   // 64 rows x 256 k f16, fragment order
  __shared__ int rowmaxI[MB];
  __shared__ int cnt[MB];
  __shared__ int ncnt[MB];
  __shared__ unsigned short cand[MB][CAP];     // 8 KB
  __shared__ float scoref[MB][CAP];            // 16 KB; total ~58 KB -> 2 blocks/CU

  const int tid  = threadIdx.x;
  const int lane = tid & 63;
  const int wid  = tid >> 6;     // 0..7
  const int l15  = lane & 15;
  const int quad = lane >> 4;
  const int rw   = wid >> 2;     // 0..1 : 32-row half
  const int cq   = wid & 3;      // 0..3 : code quarter
  const int r0   = blockIdx.x * MB;

  for (int i = tid; i < MB; i += THREADS) { rowmaxI[i] = 0; cnt[i] = 0; ncnt[i] = 0; }

  // stage A (clip + f16, chunk-major fragment order: 64 rows x 256 k = 2048 units)
  #pragma unroll
  for (int j = 0; j < 4; ++j) {
    int c = j * THREADS + tid;          // 0..2047
    int ms = c >> 9, kc = (c >> 6) & 7, ln = c & 63;
    int row = ms * 16 + (ln & 15);
    int k0 = kc * 32 + (ln >> 4) * 8;
    const float* ap = xin + (size_t)(r0 + row) * D + k0;
    f4_t v0 = *(const f4_t*)ap, v1 = *(const f4_t*)(ap + 4);
    h8_t h;
    h[0] = (_Float16)clipf(v0[0]); h[1] = (_Float16)clipf(v0[1]);
    h[2] = (_Float16)clipf(v0[2]); h[3] = (_Float16)clipf(v0[3]);
    h[4] = (_Float16)clipf(v1[0]); h[5] = (_Float16)clipf(v1[1]);
    h[6] = (_Float16)clipf(v1[2]); h[7] = (_Float16)clipf(v1[3]);
    *(h8_t*)(Astage + (size_t)c * 16) = h;
  }
  __syncthreads();

  // A fragments -> registers: 32 rows per wave (rw half), 64 VGPR
  h8_t afrag[2][8];
  #pragma unroll
  for (int m = 0; m < 2; ++m)
    #pragma unroll
    for (int kc = 0; kc < 8; ++kc)
      afrag[m][kc] = *(const h8_t*)(Astage +
          (size_t)(((rw * 2 + m) * 512 + kc * 64 + lane) * 16));

  // per-lane running row maxes (group-uniform via maxrow16): rml[m][r]
  float rml[2][4];
  #pragma unroll
  for (int m = 0; m < 2; ++m)
    #pragma unroll
    for (int r = 0; r < 4; ++r) rml[m][r] = -1e30f;

  // ---- K-loop: half-slot split (R14 form, proven no-spill).
  h8_t bufA[4], bufB[4]; float ekcur;
  {
    const _Float16* bb = femb + (size_t)cq * 4096 + lane * 8;
    #pragma unroll
    for (int kc = 0; kc < 4; ++kc) bufA[kc] = *(const h8_t*)(bb + kc * 512);
    #pragma unroll
    for (int kc = 0; kc < 4; ++kc) bufB[kc] = *(const h8_t*)(bb + (4 + kc) * 512);
    ekcur = ekkb[cq * 16 + l15];
  }

  for (int s = 0; s < SLOTS; ++s) {
    const int sn = (s + 1 < SLOTS) ? s + 1 : s;   // clamped prefetch (in-bounds)
    const _Float16* bbn = femb + (size_t)(sn * 4 + cq) * 4096 + lane * 8;

    f4_t acc[2];
    #pragma unroll
    for (int m = 0; m < 2; ++m) { f4_t z = {0.f, 0.f, 0.f, 0.f}; acc[m] = z; }

    // half 0: consume bufA, then immediately re-target it at next slot
    #pragma unroll
    for (int kc = 0; kc < 4; ++kc)
      #pragma unroll
      for (int m = 0; m < 2; ++m)
        acc[m] = __builtin_amdgcn_mfma_f32_16x16x32_f16(afrag[m][kc], bufA[kc], acc[m], 0, 0, 0);
    #pragma unroll
    for (int kc = 0; kc < 4; ++kc) bufA[kc] = *(const h8_t*)(bbn + kc * 512);

    // half 1: consume bufB, then re-target it at next slot
    #pragma unroll
    for (int kc = 0; kc < 4; ++kc)
      #pragma unroll
      for (int m = 0; m < 2; ++m)
        acc[m] = __builtin_amdgcn_mfma_f32_16x16x32_f16(afrag[m][4 + kc], bufB[kc], acc[m], 0, 0, 0);
    #pragma unroll
    for (int kc = 0; kc < 4; ++kc) bufB[kc] = *(const h8_t*)(bbn + (4 + kc) * 512);

    float eknext = ekkb[(sn * 4 + cq) * 16 + l15];

    // ---- epilogue: GATED register cut — quiet slots cost ~8 VALU ops per m ----
    const int ch = s * 4 + cq;
    #pragma unroll
    for (int m = 0; m < 2; ++m) {
      float ts[4];
      #pragma unroll
      for (int r = 0; r < 4; ++r) ts[r] = acc[m][r] - ekcur;
      bool hot = (ts[0] >= rml[m][0] - MARGIN) | (ts[1] >= rml[m][1] - MARGIN)
               | (ts[2] >= rml[m][2] - MARGIN) | (ts[3] >= rml[m][3] - MARGIN);
      if (__any(hot)) {
        #pragma unroll
        for (int r = 0; r < 4; ++r) {
          float mm = maxrow16(ts[r]);            // group max -> uniform in 16 lanes
          rml[m][r] = fmaxf(rml[m][r], mm);      // running row max, registers only
          if (ts[r] >= rml[m][r] - MARGIN) {
            int row_ = rw * 32 + m * 16 + quad * 4 + r;
            int sidx = atomicAdd(&cnt[row_], 1);
            if (sidx < CAP) {
              cand[row_][sidx]   = (unsigned short)(ch * 16 + l15);
              scoref[row_][sidx] = ts[r];
            }
          }
        }
      }
    }
    ekcur = eknext;

    // cross-wave tightening every 8 slots (4 cq waves share rows) + L2 sync
    if ((s & 7) == 7) {
      #pragma unroll
      for (int m = 0; m < 2; ++m)
        #pragma unroll
        for (int r = 0; r < 4; ++r) {
          int row_ = rw * 32 + m * 16 + quad * 4 + r;
          if (l15 == 0) atomicMax(&rowmaxI[row_], __float_as_int(rml[m][r]));
        }
      __syncthreads();
      #pragma unroll
      for (int m = 0; m < 2; ++m)
        #pragma unroll
        for (int r = 0; r < 4; ++r) {
          int row_ = rw * 32 + m * 16 + quad * 4 + r;
          rml[m][r] = fmaxf(rml[m][r], __int_as_float(rowmaxI[row_]));
        }
    }
  }
  __syncthreads();   // rowmaxI final (published at s=127), cnt/cand final

  // ---- compact vs FINAL row max; overflow rows -> full-rescan sentinel ----
  {
    const int row = tid >> 3, j = tid & 7;       // 8 threads per row
    const int c = cnt[row];
    if (c <= CAP) {                              // complete list: safe to compact
      const float cut = __int_as_float(rowmaxI[row]) - MARGIN;
      for (int jj = j; jj < c; jj += 8) {
        if (scoref[row][jj] >= cut) {
          int ns = atomicAdd(&ncnt[row], 1);
          gcand[(size_t)(r0 + row) * CAP + ns] = cand[row][jj];
        }
      }
    }
  }
  __syncthreads();
  if (tid < MB) {
    int c = cnt[tid];
    gcnt[r0 + tid] = (c > CAP) ? -1 : ncnt[tid];   // -1 => rescore full scan
  }
}

// ---------------- rescore: nc==1 fast path + exact slow path + full-scan fallback ----------------
__global__ void __launch_bounds__(512)
vq_rescore(const float* __restrict__ xin, const float* __restrict__ emb,
           const float* __restrict__ senp, const int* __restrict__ gcnt,
           const unsigned short* __restrict__ gcand, float* __restrict__ out,
           float* __restrict__ lossacc) {
  __shared__ float xrow[8][D];
  __shared__ float rpart[8][16];
  __shared__ float blksum;
  const int tid  = threadIdx.x;
  const int lane = tid & 63;
  const int wid  = tid >> 6;     // 0..7
  const int g    = lane >> 3;    // candidate slot within batch (0..7)
  const int e    = lane & 7;     // 32-elem octant (0..7)
  const int r0   = blockIdx.x * 64;
  if (tid == 0) blksum = 0.0f;
  __syncthreads();

  const int lane4 = lane * 4;
  float lacc = 0.0f;             // per-lane loss accumulator (deferred reduce)

  // classify this wave's 8 rows (row = wid + rr*8)
  int ncs[8], k0s[8];
  #pragma unroll
  for (int rr = 0; rr < 8; ++rr) {
    int row = r0 + wid + rr * 8;
    ncs[rr] = gcnt[row];
    k0s[rr] = gcand[(size_t)row * CAP];
  }

  // ---- fast rows: batched independent loads (one latency window) ----
  f4_t evs[8], xvs[8];
  #pragma unroll
  for (int rr = 0; rr < 8; ++rr) {
    if (ncs[rr] == 1) {          // wave-uniform branch
      int row = r0 + wid + rr * 8;
      xvs[rr] = *(const f4_t*)(xin + (size_t)row * D + lane4);
      evs[rr] = *(const f4_t*)(emb + (size_t)(k0s[rr] & (KCODES - 1)) * D + lane4);
    }
  }
  #pragma unroll
  for (int rr = 0; rr < 8; ++rr) {
    if (ncs[rr] == 1) {
      int row = r0 + wid + rr * 8;
      f4_t xv = xvs[rr];
      xv[0] = clipf(xv[0]); xv[1] = clipf(xv[1]);
      xv[2] = clipf(xv[2]); xv[3] = clipf(xv[3]);
      f4_t ev = evs[rr];
      *(f4_t*)(out + (size_t)row * D + lane4) = ev;
      #pragma unroll
      for (int i = 0; i < 4; ++i) { float df = ev[i] - xv[i]; lacc += df * df; }
    }
  }

  // ---- slow rows: exact rescore over candidates (or all codes if nc<0) ----
  for (int rr = 0; rr < 8; ++rr) {
    if (ncs[rr] != 1) {          // wave-uniform
      const int row = wid + rr * 8;
      f4_t xv = *(const f4_t*)(xin + (size_t)(r0 + row) * D + lane4);
      xv[0] = clipf(xv[0]); xv[1] = clipf(xv[1]);
      xv[2] = clipf(xv[2]); xv[3] = clipf(xv[3]);
      *(f4_t*)&xrow[wid][lane4] = xv;
      __builtin_amdgcn_wave_barrier();
      if (lane < 16) {   // numpy pairwise sum of x^2 (exact order)
        const int hf = lane >> 3, jj = lane & 7;
        const float* base = &xrow[wid][hf * 128 + jj];
        float v = base[0];
        float rs = v * v;
        #pragma unroll
        for (int m = 1; m < 16; ++m) { v = base[8 * m]; rs += v * v; }
        rpart[wid][lane] = rs;
      }
      __builtin_amdgcn_wave_barrier();
      float p[16];
      #pragma unroll
      for (int j = 0; j < 16; ++j) p[j] = rpart[wid][j];
      float h0 = ((p[0] + p[1]) + (p[2] + p[3])) + ((p[4] + p[5]) + (p[6] + p[7]));
      float h1 = ((p[8] + p[9]) + (p[10] + p[11])) + ((p[12] + p[13]) + (p[14] + p[15]));
      float sx = h0 + h1;

      // hoist this lane's x octant (32 floats)
      f4_t xo[8];
      #pragma unroll
      for (int u = 0; u < 8; ++u) xo[u] = *(const f4_t*)&xrow[wid][e * 32 + u * 4];

      const int nc = ncs[rr];
      const bool fullscan = (nc < 0);
      const int niter = fullscan ? (KCODES >> 3) : ((nc + 7) >> 3);
      const unsigned short* cl = gcand + (size_t)(r0 + row) * CAP;
      float bd = INFINITY; int bk = 0x7fffffff;
      for (int bi = 0; bi < niter; ++bi) {
        int ci = bi * 8 + g;
        bool valid = fullscan ? true : (ci < nc);
        int k = fullscan ? ci : (valid ? (int)cl[ci] : 0);
        const float* ep = emb + (size_t)k * D + e * 32;
        double dd = 0.0;
        #pragma unroll
        for (int u = 0; u < 8; ++u) {
          f4_t ev = *(const f4_t*)(ep + u * 4);
          dd += (double)xo[u][0] * (double)ev[0] + (double)xo[u][1] * (double)ev[1]
              + (double)xo[u][2] * (double)ev[2] + (double)xo[u][3] * (double)ev[3];
        }
        dd += __shfl_xor(dd, 1, 64);
        dd += __shfl_xor(dd, 2, 64);
        dd += __shfl_xor(dd, 4, 64);   // all 8 lanes of the group hold the full dot
        float T1 = sx + senp[k];       // fp32, numpy op order
        float T2 = (float)(2.0 * dd);
        float d  = valid ? (T1 - T2) : INFINITY;
        int   kk = valid ? k : 0x7fffffff;
        if (d < bd || (d == bd && kk < bk)) { bd = d; bk = kk; }
      }
      // cross-group lexicographic argmin (associative & commutative -> exact)
      #pragma unroll
      for (int off = 8; off < 64; off <<= 1) {
        float od = __shfl_xor(bd, off, 64);
        int   ok = __shfl_xor(bk, off, 64);
        if (od < bd || (od == bd && ok < bk)) { bd = od; bk = ok; }
      }
      bk &= (KCODES - 1);   // crash-guard (bk valid by construction; belt+braces)

      f4_t ev = *(const f4_t*)(emb + (size_t)bk * D + lane4);
      *(f4_t*)(out + (size_t)(r0 + row) * D + lane4) = ev;
      #pragma unroll
      for (int i = 0; i < 4; ++i) { float df = ev[i] - xv[i]; lacc += df * df; }
    }
  }

  // one reduce per wave, one LDS atomic per wave, one global atomic per block
  #pragma unroll
  for (int off = 1; off < 64; off <<= 1) lacc += __shfl_xor(lacc, off, 64);
  if (lane == 0) atomicAdd(&blksum, lacc);
  __syncthreads();
  if (tid == 0) atomicAdd(lossacc, blksum);
}

// ---------------- finalize loss ----------------
__global__ void vq_fin(const float* __restrict__ lossacc, float* __restrict__ out) {
  out[NOUT] = 1.25f * lossacc[0] / 8388608.0f;
}

extern "C" void kernel_launch(void* const* d_in, const int* in_sizes, int n_in,
                              void* d_out, int out_size, void* d_ws, size_t ws_size,
                              hipStream_t stream) {
  const float* xin = (const float*)d_in[0];
  const float* emb = (const float*)d_in[1];
  float* out = (float*)d_out;
  _Float16* femb = (_Float16*)d_ws;                 // 4 MB (512 chunks x 8 KB)
  float* F       = (float*)d_ws + 1048576;
  float* senp    = F;                               // 8192
  float* ekkb    = F + 8192;                        // 8192
  float* lossacc = F + 16384;                       // 1
  int*   gcnt    = (int*)(F + 16640);               // 32768 ints
  unsigned short* gcand = (unsigned short*)(F + 16640 + 32768);  // 32768*64 u16
  vq_packsetup<<<dim3(1024), dim3(256), 0, stream>>>(emb, femb, senp, ekkb, lossacc);
  vq_score<<<dim3(NROWS / MB), dim3(THREADS), 0, stream>>>(xin, femb, ekkb, gcnt, gcand);
  vq_rescore<<<dim3(NROWS / 64), dim3(512), 0, stream>>>(xin, emb, senp, gcnt, gcand, out, lossacc);
  vq_fin<<<dim3(1), dim3(1), 0, stream>>>(lossacc, out);
}

// Round 12
// 295.404 us; speedup vs baseline: 1.0700x; 1.0251x over previous
//
#include <hip/hip_runtime.h>

// VectorQuantizer on MI355X — R20 (= R19 resubmitted; prior round was an
// infra failure: "MI355X container failed twice", no kernel signal).
// R18 post-mortem: gated register cut = 204us, still > R12's 178 (per-wave cut
// looser -> 2.6x insert traffic). Epilogue variants exhausted; R12's epilogue
// is best. Consolidated binder: vector-load return path at 38 B/cy/CU (128KB/
// CU-slot / 3375cy), invariant under occupancy/distance/L2-traffic changes —
// yet L2 ubench sustains 56 B/cy/CU. Untested theory: L2-CHANNEL CAMPING — all
// blocks sweep femb in the same slot order (sync-aligned), so ~256 CUs hit the
// SAME 32KB concurrently. R20 = R12 score verbatim (single-buffer K-loop +
// shared-LDS-atomicMax epilogue) + CAP-64/overflow-fallback rails (R17) +
// per-block slot phase off=(bid*37)&127 to spread L2 pressure. Margin logic is
// order-independent -> superset invariant intact. Rescore/packsetup = R18.

#define D        256
#define KCODES   8192
#define NROWS    32768
#define MB       64       // rows per block (score)
#define SLOTS    128      // chunk-slots per wave (512 chunks / 4 code-quarters)
#define THREADS  512
#define CAP      64
#define MARGIN   0.03f    // f16 score err bound ~7e-3
#define BIAS     32.0f    // scores shifted positive so int-compare == float-compare
#define NOUT     8388608

typedef _Float16 h8_t __attribute__((ext_vector_type(8)));
typedef float    f4_t __attribute__((ext_vector_type(4)));

__device__ __forceinline__ float clipf(float v) { return fminf(1.0f, fmaxf(-1.0f, v)); }

#define DPP_ROR(x, n) __int_as_float(__builtin_amdgcn_update_dpp( \
    0, __float_as_int(x), 0x120 + (n), 0xF, 0xF, true))
__device__ __forceinline__ float maxrow16(float x) {
  x = fmaxf(x, DPP_ROR(x, 1));
  x = fmaxf(x, DPP_ROR(x, 2));
  x = fmaxf(x, DPP_ROR(x, 4));
  x = fmaxf(x, DPP_ROR(x, 8));
  return x;
}

// ---- pack f16 codebook, chunk-major fragment order + numpy-order sum(e^2) ----
__global__ void vq_packsetup(const float* __restrict__ emb, _Float16* __restrict__ femb,
                             float* __restrict__ senp, float* __restrict__ ekkb,
                             float* __restrict__ lossacc) {
  const int t = blockIdx.x;   // 1024 blocks
  if (t == 0 && threadIdx.x == 0) lossacc[0] = 0.0f;
  {
    int g = t * 256 + threadIdx.x;   // one global 16B unit per thread (262144)
    int ch = g >> 9, u = g & 511;
    int kc = u >> 6, ln = u & 63;
    int code = ch * 16 + (ln & 15);
    int k0 = kc * 32 + (ln >> 4) * 8;
    const float* sp = emb + (size_t)code * D + k0;
    f4_t v0 = *(const f4_t*)sp, v1 = *(const f4_t*)(sp + 4);
    h8_t h;
    h[0] = (_Float16)v0[0]; h[1] = (_Float16)v0[1];
    h[2] = (_Float16)v0[2]; h[3] = (_Float16)v0[3];
    h[4] = (_Float16)v1[0]; h[5] = (_Float16)v1[1];
    h[6] = (_Float16)v1[2]; h[7] = (_Float16)v1[3];
    *(h8_t*)(femb + (size_t)g * 8) = h;
  }
  if (t < 256) {   // senp/ekkb: byte-identical computation to previous rounds
    const int lane = threadIdx.x & 63;
    const int w    = threadIdx.x >> 6;
    const int jdx  = lane & 15, hf = jdx >> 3, jj = jdx & 7;
    #pragma unroll
    for (int cc = 0; cc < 2; ++cc) {
      int k = t * 32 + w * 8 + cc * 4 + (lane >> 4);
      const float* base = emb + (size_t)k * D + hf * 128 + jj;
      float v = base[0];
      float r = v * v;
      #pragma unroll
      for (int m = 1; m < 16; ++m) { v = base[8 * m]; r += v * v; }
      r += __shfl_xor(r, 1, 64);
      r += __shfl_xor(r, 2, 64);
      r += __shfl_xor(r, 4, 64);
      r += __shfl_xor(r, 8, 64);
      if (jdx == 0) { senp[k] = r; ekkb[k] = 0.5f * r - BIAS; }
    }
  }
}

// ---------------- score: MFMA + margin filter -> COMPACTED candidate lists ----------------
__global__ void __launch_bounds__(THREADS, 4)
vq_score(const float* __restrict__ xin, const _Float16* __restrict__ femb,
         const float* __restrict__ ekkb, int* __restrict__ gcnt,
         unsigned short* __restrict__ gcand) {
  __shared__ alignas(16) char Astage[32768];   // 64 rows x 256 k f16, fragment order
  __shared__ int rowmaxI[MB];
  __shared__ int cnt[MB];
  __shared__ int ncnt[MB];
  __shared__ unsigned short cand[MB][CAP];     // 8 KB
  __shared__ float scoref[MB][CAP];            // 16 KB; total ~58 KB -> 2 blocks/CU

  const int tid  = threadIdx.x;
  const int lane = tid & 63;
  const int wid  = tid >> 6;     // 0..7
  const int l15  = lane & 15;
  const int quad = lane >> 4;
  const int rw   = wid >> 2;     // 0..1 : 32-row half
  const int cq   = wid & 3;      // 0..3 : code quarter
  const int r0   = blockIdx.x * MB;
  const int off  = (blockIdx.x * 37) & 127;    // per-block slot phase (L2 de-camping)

  for (int i = tid; i < MB; i += THREADS) { rowmaxI[i] = 0; cnt[i] = 0; ncnt[i] = 0; }

  // stage A (clip + f16, chunk-major fragment order: 64 rows x 256 k = 2048 units)
  #pragma unroll
  for (int j = 0; j < 4; ++j) {
    int c = j * THREADS + tid;          // 0..2047
    int ms = c >> 9, kc = (c >> 6) & 7, ln = c & 63;
    int row = ms * 16 + (ln & 15);
    int k0 = kc * 32 + (ln >> 4) * 8;
    const float* ap = xin + (size_t)(r0 + row) * D + k0;
    f4_t v0 = *(const f4_t*)ap, v1 = *(const f4_t*)(ap + 4);
    h8_t h;
    h[0] = (_Float16)clipf(v0[0]); h[1] = (_Float16)clipf(v0[1]);
    h[2] = (_Float16)clipf(v0[2]); h[3] = (_Float16)clipf(v0[3]);
    h[4] = (_Float16)clipf(v1[0]); h[5] = (_Float16)clipf(v1[1]);
    h[6] = (_Float16)clipf(v1[2]); h[7] = (_Float16)clipf(v1[3]);
    *(h8_t*)(Astage + (size_t)c * 16) = h;
  }
  __syncthreads();

  // A fragments -> registers: 32 rows per wave (rw half), 64 VGPR
  h8_t afrag[2][8];
  #pragma unroll
  for (int m = 0; m < 2; ++m)
    #pragma unroll
    for (int kc = 0; kc < 8; ++kc)
      afrag[m][kc] = *(const h8_t*)(Astage +
          (size_t)(((rw * 2 + m) * 512 + kc * 64 + lane) * 16));

  float Gm[2];
  Gm[0] = -1e30f; Gm[1] = -1e30f;

  // ---- K-loop: R12 single-buffer form (proven 178us), slots visited in
  // per-block phase order sc = (s+off)&127 to spread L2 channel pressure.
  h8_t bcur[8]; float ekcur;
  {
    const _Float16* bb = femb + (size_t)(off * 4 + cq) * 4096 + lane * 8;
    #pragma unroll
    for (int kc = 0; kc < 8; ++kc) bcur[kc] = *(const h8_t*)(bb + kc * 512);
    ekcur = ekkb[(off * 4 + cq) * 16 + l15];
  }

  for (int s = 0; s < SLOTS; ++s) {
    const int sc  = (s + off) & 127;              // current slot
    const int snx = (s + 1 + off) & 127;          // next (wraps; always in-bounds)

    f4_t acc[2];
    #pragma unroll
    for (int m = 0; m < 2; ++m) { f4_t z = {0.f, 0.f, 0.f, 0.f}; acc[m] = z; }
    #pragma unroll
    for (int kc = 0; kc < 8; ++kc)
      #pragma unroll
      for (int m = 0; m < 2; ++m)
        acc[m] = __builtin_amdgcn_mfma_f32_16x16x32_f16(afrag[m][kc], bcur[kc], acc[m], 0, 0, 0);

    // issue next-slot loads now (overwrite bcur; epilogue sits in their shadow)
    float eknext;
    {
      const _Float16* bb = femb + (size_t)(snx * 4 + cq) * 4096 + lane * 8;
      #pragma unroll
      for (int kc = 0; kc < 8; ++kc) bcur[kc] = *(const h8_t*)(bb + kc * 512);
      eknext = ekkb[(snx * 4 + cq) * 16 + l15];
    }

    const int ch = sc * 4 + cq;
    #pragma unroll
    for (int m = 0; m < 2; ++m) {
      float ts[4];
      #pragma unroll
      for (int r = 0; r < 4; ++r) ts[r] = acc[m][r] - ekcur;
      float tmx = fmaxf(fmaxf(ts[0], ts[1]), fmaxf(ts[2], ts[3]));
      if (__any(tmx > Gm[m])) {
        float cmin = 1e30f;
        #pragma unroll
        for (int r = 0; r < 4; ++r) {
          int row_ = rw * 32 + m * 16 + quad * 4 + r;
          float mm = maxrow16(ts[r]);
          if (l15 == 0) atomicMax(&rowmaxI[row_], __float_as_int(mm));
          float cut = __int_as_float(rowmaxI[row_]) - MARGIN;
          cmin = fminf(cmin, cut);
          if (ts[r] >= cut) {
            int sidx = atomicAdd(&cnt[row_], 1);
            if (sidx < CAP) {
              cand[row_][sidx]   = (unsigned short)(ch * 16 + l15);
              scoref[row_][sidx] = ts[r];
            }
          }
        }
        Gm[m] = cmin;
      }
    }
    ekcur = eknext;
    if ((s & 31) == 31) __syncthreads();   // intra-block wave alignment (L1 dedup)
  }
  __syncthreads();

  // ---- compact vs FINAL row max; overflow rows -> full-rescan sentinel ----
  {
    const int row = tid >> 3, j = tid & 7;       // 8 threads per row
    const int c = cnt[row];
    if (c <= CAP) {                              // complete list: safe to compact
      const float cut = __int_as_float(rowmaxI[row]) - MARGIN;
      for (int jj = j; jj < c; jj += 8) {
        if (scoref[row][jj] >= cut) {
          int ns = atomicAdd(&ncnt[row], 1);
          gcand[(size_t)(r0 + row) * CAP + ns] = cand[row][jj];
        }
      }
    }
  }
  __syncthreads();
  if (tid < MB) {
    int c = cnt[tid];
    gcnt[r0 + tid] = (c > CAP) ? -1 : ncnt[tid];   // -1 => rescore full scan
  }
}

// ---------------- rescore: nc==1 fast path + exact slow path + full-scan fallback ----------------
__global__ void __launch_bounds__(512)
vq_rescore(const float* __restrict__ xin, const float* __restrict__ emb,
           const float* __restrict__ senp, const int* __restrict__ gcnt,
           const unsigned short* __restrict__ gcand, float* __restrict__ out,
           float* __restrict__ lossacc) {
  __shared__ float xrow[8][D];
  __shared__ float rpart[8][16];
  __shared__ float blksum;
  const int tid  = threadIdx.x;
  const int lane = tid & 63;
  const int wid  = tid >> 6;     // 0..7
  const int g    = lane >> 3;    // candidate slot within batch (0..7)
  const int e    = lane & 7;     // 32-elem octant (0..7)
  const int r0   = blockIdx.x * 64;
  if (tid == 0) blksum = 0.0f;
  __syncthreads();

  const int lane4 = lane * 4;
  float lacc = 0.0f;             // per-lane loss accumulator (deferred reduce)

  // classify this wave's 8 rows (row = wid + rr*8)
  int ncs[8], k0s[8];
  #pragma unroll
  for (int rr = 0; rr < 8; ++rr) {
    int row = r0 + wid + rr * 8;
    ncs[rr] = gcnt[row];
    k0s[rr] = gcand[(size_t)row * CAP];
  }

  // ---- fast rows: batched independent loads (one latency window) ----
  f4_t evs[8], xvs[8];
  #pragma unroll
  for (int rr = 0; rr < 8; ++rr) {
    if (ncs[rr] == 1) {          // wave-uniform branch
      int row = r0 + wid + rr * 8;
      xvs[rr] = *(const f4_t*)(xin + (size_t)row * D + lane4);
      evs[rr] = *(const f4_t*)(emb + (size_t)(k0s[rr] & (KCODES - 1)) * D + lane4);
    }
  }
  #pragma unroll
  for (int rr = 0; rr < 8; ++rr) {
    if (ncs[rr] == 1) {
      int row = r0 + wid + rr * 8;
      f4_t xv = xvs[rr];
      xv[0] = clipf(xv[0]); xv[1] = clipf(xv[1]);
      xv[2] = clipf(xv[2]); xv[3] = clipf(xv[3]);
      f4_t ev = evs[rr];
      *(f4_t*)(out + (size_t)row * D + lane4) = ev;
      #pragma unroll
      for (int i = 0; i < 4; ++i) { float df = ev[i] - xv[i]; lacc += df * df; }
    }
  }

  // ---- slow rows: exact rescore over candidates (or all codes if nc<0) ----
  for (int rr = 0; rr < 8; ++rr) {
    if (ncs[rr] != 1) {          // wave-uniform
      const int row = wid + rr * 8;
      f4_t xv = *(const f4_t*)(xin + (size_t)(r0 + row) * D + lane4);
      xv[0] = clipf(xv[0]); xv[1] = clipf(xv[1]);
      xv[2] = clipf(xv[2]); xv[3] = clipf(xv[3]);
      *(f4_t*)&xrow[wid][lane4] = xv;
      __builtin_amdgcn_wave_barrier();
      if (lane < 16) {   // numpy pairwise sum of x^2 (exact order)
        const int hf = lane >> 3, jj = lane & 7;
        const float* base = &xrow[wid][hf * 128 + jj];
        float v = base[0];
        float rs = v * v;
        #pragma unroll
        for (int m = 1; m < 16; ++m) { v = base[8 * m]; rs += v * v; }
        rpart[wid][lane] = rs;
      }
      __builtin_amdgcn_wave_barrier();
      float p[16];
      #pragma unroll
      for (int j = 0; j < 16; ++j) p[j] = rpart[wid][j];
      float h0 = ((p[0] + p[1]) + (p[2] + p[3])) + ((p[4] + p[5]) + (p[6] + p[7]));
      float h1 = ((p[8] + p[9]) + (p[10] + p[11])) + ((p[12] + p[13]) + (p[14] + p[15]));
      float sx = h0 + h1;

      // hoist this lane's x octant (32 floats)
      f4_t xo[8];
      #pragma unroll
      for (int u = 0; u < 8; ++u) xo[u] = *(const f4_t*)&xrow[wid][e * 32 + u * 4];

      const int nc = ncs[rr];
      const bool fullscan = (nc < 0);
      const int niter = fullscan ? (KCODES >> 3) : ((nc + 7) >> 3);
      const unsigned short* cl = gcand + (size_t)(r0 + row) * CAP;
      float bd = INFINITY; int bk = 0x7fffffff;
      for (int bi = 0; bi < niter; ++bi) {
        int ci = bi * 8 + g;
        bool valid = fullscan ? true : (ci < nc);
        int k = fullscan ? ci : (valid ? (int)cl[ci] : 0);
        const float* ep = emb + (size_t)k * D + e * 32;
        double dd = 0.0;
        #pragma unroll
        for (int u = 0; u < 8; ++u) {
          f4_t ev = *(const f4_t*)(ep + u * 4);
          dd += (double)xo[u][0] * (double)ev[0] + (double)xo[u][1] * (double)ev[1]
              + (double)xo[u][2] * (double)ev[2] + (double)xo[u][3] * (double)ev[3];
        }
        dd += __shfl_xor(dd, 1, 64);
        dd += __shfl_xor(dd, 2, 64);
        dd += __shfl_xor(dd, 4, 64);   // all 8 lanes of the group hold the full dot
        float T1 = sx + senp[k];       // fp32, numpy op order
        float T2 = (float)(2.0 * dd);
        float d  = valid ? (T1 - T2) : INFINITY;
        int   kk = valid ? k : 0x7fffffff;
        if (d < bd || (d == bd && kk < bk)) { bd = d; bk = kk; }
      }
      // cross-group lexicographic argmin (associative & commutative -> exact)
      #pragma unroll
      for (int off = 8; off < 64; off <<= 1) {
        float od = __shfl_xor(bd, off, 64);
        int   ok = __shfl_xor(bk, off, 64);
        if (od < bd || (od == bd && ok < bk)) { bd = od; bk = ok; }
      }
      bk &= (KCODES - 1);   // crash-guard (bk valid by construction; belt+braces)

      f4_t ev = *(const f4_t*)(emb + (size_t)bk * D + lane4);
      *(f4_t*)(out + (size_t)(r0 + row) * D + lane4) = ev;
      #pragma unroll
      for (int i = 0; i < 4; ++i) { float df = ev[i] - xv[i]; lacc += df * df; }
    }
  }

  // one reduce per wave, one LDS atomic per wave, one global atomic per block
  #pragma unroll
  for (int off = 1; off < 64; off <<= 1) lacc += __shfl_xor(lacc, off, 64);
  if (lane == 0) atomicAdd(&blksum, lacc);
  __syncthreads();
  if (tid == 0) atomicAdd(lossacc, blksum);
}

// ---------------- finalize loss ----------------
__global__ void vq_fin(const float* __restrict__ lossacc, float* __restrict__ out) {
  out[NOUT] = 1.25f * lossacc[0] / 8388608.0f;
}

extern "C" void kernel_launch(void* const* d_in, const int* in_sizes, int n_in,
                              void* d_out, int out_size, void* d_ws, size_t ws_size,
                              hipStream_t stream) {
  const float* xin = (const float*)d_in[0];
  const float* emb = (const float*)d_in[1];
  float* out = (float*)d_out;
  _Float16* femb = (_Float16*)d_ws;                 // 4 MB (512 chunks x 8 KB)
  float* F       = (float*)d_ws + 1048576;
  float* senp    = F;                               // 8192
  float* ekkb    = F + 8192;                        // 8192
  float* lossacc = F + 16384;                       // 1
  int*   gcnt    = (int*)(F + 16640);               // 32768 ints
  unsigned short* gcand = (unsigned short*)(F + 16640 + 32768);  // 32768*64 u16
  vq_packsetup<<<dim3(1024), dim3(256), 0, stream>>>(emb, femb, senp, ekkb, lossacc);
  vq_score<<<dim3(NROWS / MB), dim3(THREADS), 0, stream>>>(xin, femb, ekkb, gcnt, gcand);
  vq_rescore<<<dim3(NROWS / 64), dim3(512), 0, stream>>>(xin, emb, senp, gcnt, gcand, out, lossacc);
  vq_fin<<<dim3(1), dim3(1), 0, stream>>>(lossacc, out);
}

// Round 13
// 278.194 us; speedup vs baseline: 1.1362x; 1.0619x over previous
//
#include <hip/hip_runtime.h>

// VectorQuantizer on MI355X — R21.
// R20 post-mortem: phase offset REFUTED camping theory (6th dead): FETCH 33->56MB
// (blocks stopped sharing L2 lines) yet dur 178->186 — beyond-L1 misses are free.
// Surviving model: slot = L1->VGPR return path (~64B/cy/CU: 128KB/CU-slot=2048cy)
// + ~1300cy epilogue/dependency tail = 3375cy. M=64/wave (128 A-VGPR -> 2 w/SIMD,
// R8 loss) and LDS split-port (1 blk/CU, R10 loss) are measured dead ends.
// R21 consolidates: (1) revert phase offset (R12 sweep order, proven 178us);
// keep CAP-64 + full-scan fallback rails (R17, proven safe). (2) rescore: hoist
// xin loads for ALL 8 rows into the upfront batched window (slow rows exposed
// ~600cy serial latency each); slow path consumes preloaded values (identical
// semantics). Everything else byte-identical to the proven kernels.

#define D        256
#define KCODES   8192
#define NROWS    32768
#define MB       64       // rows per block (score)
#define SLOTS    128      // chunk-slots per wave (512 chunks / 4 code-quarters)
#define THREADS  512
#define CAP      64
#define MARGIN   0.03f    // f16 score err bound ~7e-3
#define BIAS     32.0f    // scores shifted positive so int-compare == float-compare
#define NOUT     8388608

typedef _Float16 h8_t __attribute__((ext_vector_type(8)));
typedef float    f4_t __attribute__((ext_vector_type(4)));

__device__ __forceinline__ float clipf(float v) { return fminf(1.0f, fmaxf(-1.0f, v)); }

#define DPP_ROR(x, n) __int_as_float(__builtin_amdgcn_update_dpp( \
    0, __float_as_int(x), 0x120 + (n), 0xF, 0xF, true))
__device__ __forceinline__ float maxrow16(float x) {
  x = fmaxf(x, DPP_ROR(x, 1));
  x = fmaxf(x, DPP_ROR(x, 2));
  x = fmaxf(x, DPP_ROR(x, 4));
  x = fmaxf(x, DPP_ROR(x, 8));
  return x;
}

// ---- pack f16 codebook, chunk-major fragment order + numpy-order sum(e^2) ----
__global__ void vq_packsetup(const float* __restrict__ emb, _Float16* __restrict__ femb,
                             float* __restrict__ senp, float* __restrict__ ekkb,
                             float* __restrict__ lossacc) {
  const int t = blockIdx.x;   // 1024 blocks
  if (t == 0 && threadIdx.x == 0) lossacc[0] = 0.0f;
  {
    int g = t * 256 + threadIdx.x;   // one global 16B unit per thread (262144)
    int ch = g >> 9, u = g & 511;
    int kc = u >> 6, ln = u & 63;
    int code = ch * 16 + (ln & 15);
    int k0 = kc * 32 + (ln >> 4) * 8;
    const float* sp = emb + (size_t)code * D + k0;
    f4_t v0 = *(const f4_t*)sp, v1 = *(const f4_t*)(sp + 4);
    h8_t h;
    h[0] = (_Float16)v0[0]; h[1] = (_Float16)v0[1];
    h[2] = (_Float16)v0[2]; h[3] = (_Float16)v0[3];
    h[4] = (_Float16)v1[0]; h[5] = (_Float16)v1[1];
    h[6] = (_Float16)v1[2]; h[7] = (_Float16)v1[3];
    *(h8_t*)(femb + (size_t)g * 8) = h;
  }
  if (t < 256) {   // senp/ekkb: byte-identical computation to previous rounds
    const int lane = threadIdx.x & 63;
    const int w    = threadIdx.x >> 6;
    const int jdx  = lane & 15, hf = jdx >> 3, jj = jdx & 7;
    #pragma unroll
    for (int cc = 0; cc < 2; ++cc) {
      int k = t * 32 + w * 8 + cc * 4 + (lane >> 4);
      const float* base = emb + (size_t)k * D + hf * 128 + jj;
      float v = base[0];
      float r = v * v;
      #pragma unroll
      for (int m = 1; m < 16; ++m) { v = base[8 * m]; r += v * v; }
      r += __shfl_xor(r, 1, 64);
      r += __shfl_xor(r, 2, 64);
      r += __shfl_xor(r, 4, 64);
      r += __shfl_xor(r, 8, 64);
      if (jdx == 0) { senp[k] = r; ekkb[k] = 0.5f * r - BIAS; }
    }
  }
}

// ---------------- score: MFMA + margin filter -> COMPACTED candidate lists ----------------
__global__ void __launch_bounds__(THREADS, 4)
vq_score(const float* __restrict__ xin, const _Float16* __restrict__ femb,
         const float* __restrict__ ekkb, int* __restrict__ gcnt,
         unsigned short* __restrict__ gcand) {
  __shared__ alignas(16) char Astage[32768];   // 64 rows x 256 k f16, fragment order
  __shared__ int rowmaxI[MB];
  __shared__ int cnt[MB];
  __shared__ int ncnt[MB];
  __shared__ unsigned short cand[MB][CAP];     // 8 KB
  __shared__ float scoref[MB][CAP];            // 16 KB; total ~58 KB -> 2 blocks/CU

  const int tid  = threadIdx.x;
  const int lane = tid & 63;
  const int wid  = tid >> 6;     // 0..7
  const int l15  = lane & 15;
  const int quad = lane >> 4;
  const int rw   = wid >> 2;     // 0..1 : 32-row half
  const int cq   = wid & 3;      // 0..3 : code quarter
  const int r0   = blockIdx.x * MB;

  for (int i = tid; i < MB; i += THREADS) { rowmaxI[i] = 0; cnt[i] = 0; ncnt[i] = 0; }

  // stage A (clip + f16, chunk-major fragment order: 64 rows x 256 k = 2048 units)
  #pragma unroll
  for (int j = 0; j < 4; ++j) {
    int c = j * THREADS + tid;          // 0..2047
    int ms = c >> 9, kc = (c >> 6) & 7, ln = c & 63;
    int row = ms * 16 + (ln & 15);
    int k0 = kc * 32 + (ln >> 4) * 8;
    const float* ap = xin + (size_t)(r0 + row) * D + k0;
    f4_t v0 = *(const f4_t*)ap, v1 = *(const f4_t*)(ap + 4);
    h8_t h;
    h[0] = (_Float16)clipf(v0[0]); h[1] = (_Float16)clipf(v0[1]);
    h[2] = (_Float16)clipf(v0[2]); h[3] = (_Float16)clipf(v0[3]);
    h[4] = (_Float16)clipf(v1[0]); h[5] = (_Float16)clipf(v1[1]);
    h[6] = (_Float16)clipf(v1[2]); h[7] = (_Float16)clipf(v1[3]);
    *(h8_t*)(Astage + (size_t)c * 16) = h;
  }
  __syncthreads();

  // A fragments -> registers: 32 rows per wave (rw half), 64 VGPR
  h8_t afrag[2][8];
  #pragma unroll
  for (int m = 0; m < 2; ++m)
    #pragma unroll
    for (int kc = 0; kc < 8; ++kc)
      afrag[m][kc] = *(const h8_t*)(Astage +
          (size_t)(((rw * 2 + m) * 512 + kc * 64 + lane) * 16));

  float Gm[2];
  Gm[0] = -1e30f; Gm[1] = -1e30f;

  // ---- K-loop: R12 single-buffer form (proven 178us), natural sweep order.
  h8_t bcur[8]; float ekcur;
  {
    const _Float16* bb = femb + (size_t)cq * 4096 + lane * 8;
    #pragma unroll
    for (int kc = 0; kc < 8; ++kc) bcur[kc] = *(const h8_t*)(bb + kc * 512);
    ekcur = ekkb[cq * 16 + l15];
  }

  for (int s = 0; s < SLOTS; ++s) {
    f4_t acc[2];
    #pragma unroll
    for (int m = 0; m < 2; ++m) { f4_t z = {0.f, 0.f, 0.f, 0.f}; acc[m] = z; }
    #pragma unroll
    for (int kc = 0; kc < 8; ++kc)
      #pragma unroll
      for (int m = 0; m < 2; ++m)
        acc[m] = __builtin_amdgcn_mfma_f32_16x16x32_f16(afrag[m][kc], bcur[kc], acc[m], 0, 0, 0);

    // issue next-slot loads now (overwrite bcur; epilogue sits in their shadow)
    const int sn = (s + 1 < SLOTS) ? s + 1 : s;   // clamped prefetch (in-bounds)
    float eknext;
    {
      const _Float16* bb = femb + (size_t)(sn * 4 + cq) * 4096 + lane * 8;
      #pragma unroll
      for (int kc = 0; kc < 8; ++kc) bcur[kc] = *(const h8_t*)(bb + kc * 512);
      eknext = ekkb[(sn * 4 + cq) * 16 + l15];
    }

    const int ch = s * 4 + cq;
    #pragma unroll
    for (int m = 0; m < 2; ++m) {
      float ts[4];
      #pragma unroll
      for (int r = 0; r < 4; ++r) ts[r] = acc[m][r] - ekcur;
      float tmx = fmaxf(fmaxf(ts[0], ts[1]), fmaxf(ts[2], ts[3]));
      if (__any(tmx > Gm[m])) {
        float cmin = 1e30f;
        #pragma unroll
        for (int r = 0; r < 4; ++r) {
          int row_ = rw * 32 + m * 16 + quad * 4 + r;
          float mm = maxrow16(ts[r]);
          if (l15 == 0) atomicMax(&rowmaxI[row_], __float_as_int(mm));
          float cut = __int_as_float(rowmaxI[row_]) - MARGIN;
          cmin = fminf(cmin, cut);
          if (ts[r] >= cut) {
            int sidx = atomicAdd(&cnt[row_], 1);
            if (sidx < CAP) {
              cand[row_][sidx]   = (unsigned short)(ch * 16 + l15);
              scoref[row_][sidx] = ts[r];
            }
          }
        }
        Gm[m] = cmin;
      }
    }
    ekcur = eknext;
    if ((s & 31) == 31) __syncthreads();   // keep waves in the same L2 window
  }
  __syncthreads();

  // ---- compact vs FINAL row max; overflow rows -> full-rescan sentinel ----
  {
    const int row = tid >> 3, j = tid & 7;       // 8 threads per row
    const int c = cnt[row];
    if (c <= CAP) {                              // complete list: safe to compact
      const float cut = __int_as_float(rowmaxI[row]) - MARGIN;
      for (int jj = j; jj < c; jj += 8) {
        if (scoref[row][jj] >= cut) {
          int ns = atomicAdd(&ncnt[row], 1);
          gcand[(size_t)(r0 + row) * CAP + ns] = cand[row][jj];
        }
      }
    }
  }
  __syncthreads();
  if (tid < MB) {
    int c = cnt[tid];
    gcnt[r0 + tid] = (c > CAP) ? -1 : ncnt[tid];   // -1 => rescore full scan
  }
}

// ---------------- rescore: nc==1 fast path + exact slow path + full-scan fallback ----------------
__global__ void __launch_bounds__(512)
vq_rescore(const float* __restrict__ xin, const float* __restrict__ emb,
           const float* __restrict__ senp, const int* __restrict__ gcnt,
           const unsigned short* __restrict__ gcand, float* __restrict__ out,
           float* __restrict__ lossacc) {
  __shared__ float xrow[8][D];
  __shared__ float rpart[8][16];
  __shared__ float blksum;
  const int tid  = threadIdx.x;
  const int lane = tid & 63;
  const int wid  = tid >> 6;     // 0..7
  const int g    = lane >> 3;    // candidate slot within batch (0..7)
  const int e    = lane & 7;     // 32-elem octant (0..7)
  const int r0   = blockIdx.x * 64;
  if (tid == 0) blksum = 0.0f;
  __syncthreads();

  const int lane4 = lane * 4;
  float lacc = 0.0f;             // per-lane loss accumulator (deferred reduce)

  // classify this wave's 8 rows (row = wid + rr*8) + hoist ALL x loads into
  // one latency window (slow rows previously paid ~600cy serial each)
  int ncs[8], k0s[8];
  f4_t xvs[8];
  #pragma unroll
  for (int rr = 0; rr < 8; ++rr) {
    int row = r0 + wid + rr * 8;
    ncs[rr] = gcnt[row];
    k0s[rr] = gcand[(size_t)row * CAP];
    xvs[rr] = *(const f4_t*)(xin + (size_t)row * D + lane4);
  }

  // ---- fast rows: batched independent emb gathers ----
  f4_t evs[8];
  #pragma unroll
  for (int rr = 0; rr < 8; ++rr) {
    if (ncs[rr] == 1) {          // wave-uniform branch
      evs[rr] = *(const f4_t*)(emb + (size_t)(k0s[rr] & (KCODES - 1)) * D + lane4);
    }
  }
  #pragma unroll
  for (int rr = 0; rr < 8; ++rr) {
    if (ncs[rr] == 1) {
      int row = r0 + wid + rr * 8;
      f4_t xv = xvs[rr];
      xv[0] = clipf(xv[0]); xv[1] = clipf(xv[1]);
      xv[2] = clipf(xv[2]); xv[3] = clipf(xv[3]);
      f4_t ev = evs[rr];
      *(f4_t*)(out + (size_t)row * D + lane4) = ev;
      #pragma unroll
      for (int i = 0; i < 4; ++i) { float df = ev[i] - xv[i]; lacc += df * df; }
    }
  }

  // ---- slow rows: exact rescore over candidates (or all codes if nc<0) ----
  for (int rr = 0; rr < 8; ++rr) {
    if (ncs[rr] != 1) {          // wave-uniform
      const int row = wid + rr * 8;
      f4_t xv = xvs[rr];
      xv[0] = clipf(xv[0]); xv[1] = clipf(xv[1]);
      xv[2] = clipf(xv[2]); xv[3] = clipf(xv[3]);
      *(f4_t*)&xrow[wid][lane4] = xv;
      __builtin_amdgcn_wave_barrier();
      if (lane < 16) {   // numpy pairwise sum of x^2 (exact order)
        const int hf = lane >> 3, jj = lane & 7;
        const float* base = &xrow[wid][hf * 128 + jj];
        float v = base[0];
        float rs = v * v;
        #pragma unroll
        for (int m = 1; m < 16; ++m) { v = base[8 * m]; rs += v * v; }
        rpart[wid][lane] = rs;
      }
      __builtin_amdgcn_wave_barrier();
      float p[16];
      #pragma unroll
      for (int j = 0; j < 16; ++j) p[j] = rpart[wid][j];
      float h0 = ((p[0] + p[1]) + (p[2] + p[3])) + ((p[4] + p[5]) + (p[6] + p[7]));
      float h1 = ((p[8] + p[9]) + (p[10] + p[11])) + ((p[12] + p[13]) + (p[14] + p[15]));
      float sx = h0 + h1;

      // hoist this lane's x octant (32 floats)
      f4_t xo[8];
      #pragma unroll
      for (int u = 0; u < 8; ++u) xo[u] = *(const f4_t*)&xrow[wid][e * 32 + u * 4];

      const int nc = ncs[rr];
      const bool fullscan = (nc < 0);
      const int niter = fullscan ? (KCODES >> 3) : ((nc + 7) >> 3);
      const unsigned short* cl = gcand + (size_t)(r0 + row) * CAP;
      float bd = INFINITY; int bk = 0x7fffffff;
      for (int bi = 0; bi < niter; ++bi) {
        int ci = bi * 8 + g;
        bool valid = fullscan ? true : (ci < nc);
        int k = fullscan ? ci : (valid ? (int)cl[ci] : 0);
        const float* ep = emb + (size_t)k * D + e * 32;
        double dd = 0.0;
        #pragma unroll
        for (int u = 0; u < 8; ++u) {
          f4_t ev = *(const f4_t*)(ep + u * 4);
          dd += (double)xo[u][0] * (double)ev[0] + (double)xo[u][1] * (double)ev[1]
              + (double)xo[u][2] * (double)ev[2] + (double)xo[u][3] * (double)ev[3];
        }
        dd += __shfl_xor(dd, 1, 64);
        dd += __shfl_xor(dd, 2, 64);
        dd += __shfl_xor(dd, 4, 64);   // all 8 lanes of the group hold the full dot
        float T1 = sx + senp[k];       // fp32, numpy op order
        float T2 = (float)(2.0 * dd);
        float d  = valid ? (T1 - T2) : INFINITY;
        int   kk = valid ? k : 0x7fffffff;
        if (d < bd || (d == bd && kk < bk)) { bd = d; bk = kk; }
      }
      // cross-group lexicographic argmin (associative & commutative -> exact)
      #pragma unroll
      for (int off = 8; off < 64; off <<= 1) {
        float od = __shfl_xor(bd, off, 64);
        int   ok = __shfl_xor(bk, off, 64);
        if (od < bd || (od == bd && ok < bk)) { bd = od; bk = ok; }
      }
      bk &= (KCODES - 1);   // crash-guard (bk valid by construction; belt+braces)

      f4_t ev = *(const f4_t*)(emb + (size_t)bk * D + lane4);
      *(f4_t*)(out + (size_t)(r0 + row) * D + lane4) = ev;
      #pragma unroll
      for (int i = 0; i < 4; ++i) { float df = ev[i] - xv[i]; lacc += df * df; }
    }
  }

  // one reduce per wave, one LDS atomic per wave, one global atomic per block
  #pragma unroll
  for (int off = 1; off < 64; off <<= 1) lacc += __shfl_xor(lacc, off, 64);
  if (lane == 0) atomicAdd(&blksum, lacc);
  __syncthreads();
  if (tid == 0) atomicAdd(lossacc, blksum);
}

// ---------------- finalize loss ----------------
__global__ void vq_fin(const float* __restrict__ lossacc, float* __restrict__ out) {
  out[NOUT] = 1.25f * lossacc[0] / 8388608.0f;
}

extern "C" void kernel_launch(void* const* d_in, const int* in_sizes, int n_in,
                              void* d_out, int out_size, void* d_ws, size_t ws_size,
                              hipStream_t stream) {
  const float* xin = (const float*)d_in[0];
  const float* emb = (const float*)d_in[1];
  float* out = (float*)d_out;
  _Float16* femb = (_Float16*)d_ws;                 // 4 MB (512 chunks x 8 KB)
  float* F       = (float*)d_ws + 1048576;
  float* senp    = F;                               // 8192
  float* ekkb    = F + 8192;                        // 8192
  float* lossacc = F + 16384;                       // 1
  int*   gcnt    = (int*)(F + 16640);               // 32768 ints
  unsigned short* gcand = (unsigned short*)(F + 16640 + 32768);  // 32768*64 u16
  vq_packsetup<<<dim3(1024), dim3(256), 0, stream>>>(emb, femb, senp, ekkb, lossacc);
  vq_score<<<dim3(NROWS / MB), dim3(THREADS), 0, stream>>>(xin, femb, ekkb, gcnt, gcand);
  vq_rescore<<<dim3(NROWS / 64), dim3(512), 0, stream>>>(xin, emb, senp, gcnt, gcand, out, lossacc);
  vq_fin<<<dim3(1), dim3(1), 0, stream>>>(lossacc, out);
}